// Round 3
// baseline (363.535 us; speedup 1.0000x reference)
//
#include <hip/hip_runtime.h>
#include <math.h>

#define SD 768
#define SB 16
#define SM 8
#define SS 2048
#define TOK_ROW 2049
#define NEG_INF (-__builtin_inff())

// ws layout (float offsets).
#define OFF_PPOOL   0          // 32*16*2304
#define OFF_PO      1179648    // 32*16*6144
#define OFF_PML     4325376    // 32*16*16
#define OFF_PTRAD   4333568    // 16*2304
#define OFF_PLEARN  4370432    // 16*6912
#define OFF_P1A     4481024    // 9*12288
#define OFF_P1B     4591616    // 27*12288
#define OFF_P2A     4947968    // 3*12288
#define OFF_P2B     4984832    // 3*12288

__device__ __forceinline__ int clen(int v) { return v < 1 ? 1 : (v > SS ? SS : v); }

// ============ K1: fused pool-partials + LN + scores + local-softmax + O_c =====
// grid (32 s-chunks, 16 b), 256 thr = 4 waves; wave w owns rows [c0+16w, +16)
__global__ __launch_bounds__(256, 2) void k1_flash(
    const float* __restrict__ tokens, const int* __restrict__ lengths,
    const float* __restrict__ q, const float* __restrict__ lns,
    const float* __restrict__ lnb, float* __restrict__ ppool,
    float* __restrict__ pO, float* __restrict__ pml) {
  int c = blockIdx.x, b = blockIdx.y;
  int len = clen(lengths[b]);
  int c0 = c * 64;
  if (c0 >= len) return;
  int tid = threadIdx.x, w = tid >> 6, lane = tid & 63;
  int mm = lane & 7;

  __shared__ float p_lds[4][16][8];       // 2 KB   scores -> probs
  __shared__ float pool_lds[4][3][SD];    // 36 KB
  __shared__ float O_lds[SM][SD];         // 24 KB
  __shared__ float mx_lds[8];

  // init p_lds to -inf (invalid rows contribute exp(-inf)=0)
  {
    float* pf = &p_lds[0][0][0];
    for (int i = tid; i < 512; i += 256) pf[i] = NEG_INF;
  }

  // ---- q setup: qs = q*scale (regs), qs1[m]=sum(qs), qb[m]=q.lnb ----
  float4 qr[8][3];
  float qs1sel, qbsel;
  {
    float4 l4[3], lb4[3];
    #pragma unroll
    for (int g = 0; g < 3; ++g) {
      l4[g] = *(const float4*)(lns + g * 256 + lane * 4);
      lb4[g] = *(const float4*)(lnb + g * 256 + lane * 4);
    }
    float qs1r[8], qbr[8];
    #pragma unroll
    for (int m = 0; m < 8; ++m) {
      float s1 = 0.f, sb = 0.f;
      #pragma unroll
      for (int g = 0; g < 3; ++g) {
        float4 qv = *(const float4*)(q + m * SD + g * 256 + lane * 4);
        float4 qs;
        qs.x = qv.x * l4[g].x; qs.y = qv.y * l4[g].y;
        qs.z = qv.z * l4[g].z; qs.w = qv.w * l4[g].w;
        qr[m][g] = qs;
        s1 += qs.x + qs.y + qs.z + qs.w;
        sb += qv.x * lb4[g].x + qv.y * lb4[g].y + qv.z * lb4[g].z + qv.w * lb4[g].w;
      }
      #pragma unroll
      for (int o = 32; o; o >>= 1) { s1 += __shfl_xor(s1, o, 64); sb += __shfl_xor(sb, o, 64); }
      qs1r[m] = s1; qbr[m] = sb;
    }
    qs1sel = qs1r[0]; qbsel = qbr[0];
    #pragma unroll
    for (int m = 1; m < 8; ++m) {
      qs1sel = (mm == m) ? qs1r[m] : qs1sel;
      qbsel = (mm == m) ? qbr[m] : qbsel;
    }
  }
  __syncthreads();  // p_lds init visible before phase-1 writes

  // ---- phase 1: pooling + LN stats + scores (software-pipelined loads) ----
  float psum[12], pmax[12], pmin[12];
  #pragma unroll
  for (int j = 0; j < 12; ++j) { psum[j] = 0.f; pmax[j] = NEG_INF; pmin[j] = -NEG_INF; }

  int srow = c0 + w * 16;
  int smax = len - srow; if (smax > 16) smax = 16; if (smax < 0) smax = 0;
  const float* xrow = tokens + ((size_t)b * TOK_ROW + 1 + srow) * SD;

  float4 nx0 = {}, nx1 = {}, nx2 = {};
  if (smax > 0) {
    nx0 = *(const float4*)(xrow + lane * 4);
    nx1 = *(const float4*)(xrow + 256 + lane * 4);
    nx2 = *(const float4*)(xrow + 512 + lane * 4);
  }
  for (int i = 0; i < smax; ++i) {
    float4 x0 = nx0, x1 = nx1, x2 = nx2;
    if (i + 1 < smax) {
      const float* xq = xrow + (size_t)(i + 1) * SD;
      nx0 = *(const float4*)(xq + lane * 4);
      nx1 = *(const float4*)(xq + 256 + lane * 4);
      nx2 = *(const float4*)(xq + 512 + lane * 4);
    }
    float xv[12] = {x0.x, x0.y, x0.z, x0.w, x1.x, x1.y, x1.z, x1.w,
                    x2.x, x2.y, x2.z, x2.w};
    float s1 = 0.f, s2 = 0.f;
    #pragma unroll
    for (int j = 0; j < 12; ++j) {
      float v = xv[j];
      psum[j] += v;
      pmax[j] = fmaxf(pmax[j], v);
      pmin[j] = fminf(pmin[j], v);
      s1 += v;
      s2 += v * v;
    }
    float d[8];
    #pragma unroll
    for (int m = 0; m < 8; ++m) {
      float4 a0 = qr[m][0], a1 = qr[m][1], a2 = qr[m][2];
      d[m] = a0.x * xv[0] + a0.y * xv[1] + a0.z * xv[2] + a0.w * xv[3]
           + a1.x * xv[4] + a1.y * xv[5] + a1.z * xv[6] + a1.w * xv[7]
           + a2.x * xv[8] + a2.y * xv[9] + a2.z * xv[10] + a2.w * xv[11];
    }
    // reduce: d butterfly {1,2,4}, select by lane&7, then {8,16,32} with s1,s2
    #pragma unroll
    for (int o = 1; o <= 4; o <<= 1)
      #pragma unroll
      for (int m = 0; m < 8; ++m) d[m] += __shfl_xor(d[m], o, 64);
    float u = d[0];
    #pragma unroll
    for (int m = 1; m < 8; ++m) u = (mm == m) ? d[m] : u;
    #pragma unroll
    for (int o = 8; o <= 32; o <<= 1) {
      u += __shfl_xor(u, o, 64);
      s1 += __shfl_xor(s1, o, 64);
      s2 += __shfl_xor(s2, o, 64);
    }
    // s1,s2 still need stages {1,2,4}
    #pragma unroll
    for (int o = 1; o <= 4; o <<= 1) { s1 += __shfl_xor(s1, o, 64); s2 += __shfl_xor(s2, o, 64); }
    float mu = s1 * (1.f / 768.f);
    float var = s2 * (1.f / 768.f) - mu * mu;
    float rstd = rsqrtf(var + 1e-5f);
    float sc = (rstd * u - rstd * mu * qs1sel + qbsel) * 0.03608439182435161f;
    if (lane < 8) p_lds[w][i][lane] = sc;
  }

  // pool partials -> LDS
  #pragma unroll
  for (int g = 0; g < 3; ++g) {
    int dd = g * 256 + lane * 4;
    *(float4*)&pool_lds[w][0][dd] = make_float4(psum[g*4], psum[g*4+1], psum[g*4+2], psum[g*4+3]);
    *(float4*)&pool_lds[w][1][dd] = make_float4(pmax[g*4], pmax[g*4+1], pmax[g*4+2], pmax[g*4+3]);
    *(float4*)&pool_lds[w][2][dd] = make_float4(pmin[g*4], pmin[g*4+1], pmin[g*4+2], pmin[g*4+3]);
  }
  __syncthreads();

  // ---- chunk-local softmax on p_lds ----
  float* pf = &p_lds[0][0][0];
  if (tid < 8) {
    float mxv = NEG_INF;
    for (int r = 0; r < 64; ++r) mxv = fmaxf(mxv, pf[r * 8 + tid]);
    mx_lds[tid] = mxv;
  }
  __syncthreads();
  for (int e = tid; e < 512; e += 256) {
    int m = e & 7;
    pf[e] = __expf(pf[e] - mx_lds[m]);
  }
  __syncthreads();
  if (tid < 8) {
    float lv = 0.f;
    for (int r = 0; r < 64; ++r) lv += pf[r * 8 + tid];
    size_t base = (size_t)(c * SB + b) * 16;
    pml[base + tid] = mx_lds[tid];
    pml[base + 8 + tid] = lv;
  }

  // ---- phase 2: O_w[m][d] = sum_rows p * x  (x re-read, L2-hot, pipelined) ----
  float O[8][12];
  #pragma unroll
  for (int m = 0; m < 8; ++m)
    #pragma unroll
    for (int j = 0; j < 12; ++j) O[m][j] = 0.f;
  if (smax > 0) {
    nx0 = *(const float4*)(xrow + lane * 4);
    nx1 = *(const float4*)(xrow + 256 + lane * 4);
    nx2 = *(const float4*)(xrow + 512 + lane * 4);
  }
  for (int i = 0; i < smax; ++i) {
    float4 x0 = nx0, x1 = nx1, x2 = nx2;
    if (i + 1 < smax) {
      const float* xq = xrow + (size_t)(i + 1) * SD;
      nx0 = *(const float4*)(xq + lane * 4);
      nx1 = *(const float4*)(xq + 256 + lane * 4);
      nx2 = *(const float4*)(xq + 512 + lane * 4);
    }
    float xv[12] = {x0.x, x0.y, x0.z, x0.w, x1.x, x1.y, x1.z, x1.w,
                    x2.x, x2.y, x2.z, x2.w};
    const float4* pr = (const float4*)&p_lds[w][i][0];
    float4 pa = pr[0], pb = pr[1];
    float pm[8] = {pa.x, pa.y, pa.z, pa.w, pb.x, pb.y, pb.z, pb.w};
    #pragma unroll
    for (int m = 0; m < 8; ++m)
      #pragma unroll
      for (int j = 0; j < 12; ++j) O[m][j] += pm[m] * xv[j];
  }
  // accumulate O across waves in LDS
  #pragma unroll
  for (int r = 0; r < 4; ++r) {
    if (w == r) {
      #pragma unroll
      for (int m = 0; m < 8; ++m)
        #pragma unroll
        for (int g = 0; g < 3; ++g) {
          int dd = g * 256 + lane * 4;
          float4 mine = make_float4(O[m][g*4], O[m][g*4+1], O[m][g*4+2], O[m][g*4+3]);
          if (r == 0) {
            *(float4*)&O_lds[m][dd] = mine;
          } else {
            float4 cur = *(float4*)&O_lds[m][dd];
            cur.x += mine.x; cur.y += mine.y; cur.z += mine.z; cur.w += mine.w;
            *(float4*)&O_lds[m][dd] = cur;
          }
        }
    }
    __syncthreads();
  }

  // ---- writeout ----
  size_t obase = (size_t)(c * SB + b) * 6144;
  const float* of = &O_lds[0][0];
  for (int j = tid * 4; j < 6144; j += 1024)
    *(float4*)&pO[obase + j] = *(const float4*)&of[j];

  size_t pbase = (size_t)(c * SB + b) * 2304;
  for (int j4 = tid * 4; j4 < 2304; j4 += 1024) {
    int stat = j4 / SD, dd = j4 - stat * SD;
    float4 v0 = *(float4*)&pool_lds[0][stat][dd];
    float4 v1 = *(float4*)&pool_lds[1][stat][dd];
    float4 v2 = *(float4*)&pool_lds[2][stat][dd];
    float4 v3 = *(float4*)&pool_lds[3][stat][dd];
    float4 r;
    if (stat == 0) {
      r.x = v0.x + v1.x + v2.x + v3.x; r.y = v0.y + v1.y + v2.y + v3.y;
      r.z = v0.z + v1.z + v2.z + v3.z; r.w = v0.w + v1.w + v2.w + v3.w;
    } else if (stat == 1) {
      r.x = fmaxf(fmaxf(v0.x, v1.x), fmaxf(v2.x, v3.x));
      r.y = fmaxf(fmaxf(v0.y, v1.y), fmaxf(v2.y, v3.y));
      r.z = fmaxf(fmaxf(v0.z, v1.z), fmaxf(v2.z, v3.z));
      r.w = fmaxf(fmaxf(v0.w, v1.w), fmaxf(v2.w, v3.w));
    } else {
      r.x = fminf(fminf(v0.x, v1.x), fminf(v2.x, v3.x));
      r.y = fminf(fminf(v0.y, v1.y), fminf(v2.y, v3.y));
      r.z = fminf(fminf(v0.z, v1.z), fminf(v2.z, v3.z));
      r.w = fminf(fminf(v0.w, v1.w), fminf(v2.w, v3.w));
    }
    *(float4*)&ppool[pbase + j4] = r;
  }
}

// ============ combine: flash-rescale O + pool-reduce + clf -> ptrad, plearn ===
__global__ void k_combine(const float* __restrict__ ppool, const float* __restrict__ pO,
                          const float* __restrict__ pml, const float* __restrict__ tokens,
                          const int* __restrict__ lengths,
                          float* __restrict__ ptrad, float* __restrict__ plearn) {
  int tile = blockIdx.x, b = blockIdx.y;
  int len = clen(lengths[b]);
  int nv = (len + 63) >> 6;
  int tid = threadIdx.x;
  __shared__ float pml_lds[32][16];
  __shared__ float e_lds[32][8];
  __shared__ float Linv_lds[8];
  for (int t = tid; t < nv * 16; t += 256) {
    int cc = t >> 4, j = t & 15;
    pml_lds[cc][j] = pml[(size_t)(cc * SB + b) * 16 + j];
  }
  __syncthreads();
  if (tid < 8) {
    float M = NEG_INF;
    for (int cc = 0; cc < nv; ++cc) M = fmaxf(M, pml_lds[cc][tid]);
    float L = 0.f;
    for (int cc = 0; cc < nv; ++cc) {
      float e = __expf(pml_lds[cc][tid] - M);
      e_lds[cc][tid] = e;
      L += e * pml_lds[cc][8 + tid];
    }
    Linv_lds[tid] = 1.f / L;
  }
  __syncthreads();
  #pragma unroll
  for (int k = 0; k < 4; ++k) {
    int jj = tile * 1024 + k * 256 + tid;
    if (jj < 2304) {
      int stat = jj / SD;
      float acc = (stat == 0) ? 0.f : (stat == 1 ? NEG_INF : -NEG_INF);
      for (int cc = 0; cc < nv; ++cc) {
        float v = ppool[(size_t)(cc * SB + b) * 2304 + jj];
        if (stat == 0) acc += v;
        else if (stat == 1) acc = fmaxf(acc, v);
        else acc = fminf(acc, v);
      }
      if (stat == 0) acc /= (float)len;
      ptrad[b * 2304 + jj] = acc;
    } else if (jj < 8448) {
      int t = jj - 2304;
      int m = t / SD;
      float acc = 0.f;
      for (int cc = 0; cc < nv; ++cc)
        acc += pO[(size_t)(cc * SB + b) * 6144 + t] * e_lds[cc][m];
      plearn[b * 6912 + t] = acc * Linv_lds[m];
    } else {
      int dd = jj - 8448;
      plearn[b * 6912 + 6144 + dd] = tokens[(size_t)b * TOK_ROW * SD + dd];
    }
  }
}

// ============ layer-1 split-K GEMM partial: (16 x K) @ (K x 768) ==============
__global__ __launch_bounds__(256) void gemm_partial(
    const float* __restrict__ XA, const float* __restrict__ WA, int ktA, float* __restrict__ PA,
    const float* __restrict__ XB, const float* __restrict__ WB, float* __restrict__ PB) {
  int nt = blockIdx.x, ky = blockIdx.y;
  const float *X, *W; float* P; int kt, ktN;
  if (ky < ktA) { X = XA; W = WA; P = PA; kt = ky; ktN = ktA; }
  else { X = XB; W = WB; P = PB; kt = ky - ktA; ktN = gridDim.y - ktA; }
  int K = ktN * 256;
  int k0 = kt * 256;
  __shared__ __align__(16) float xt[256 * 20];
  __shared__ float red[4][64][17];
  int tid = threadIdx.x;
  #pragma unroll
  for (int b2 = 0; b2 < 16; ++b2) xt[tid * 20 + b2] = X[b2 * K + k0 + tid];
  __syncthreads();
  int w = tid >> 6, lane = tid & 63;
  int n = nt * 64 + lane;
  float acc[16];
  #pragma unroll
  for (int b2 = 0; b2 < 16; ++b2) acc[b2] = 0.f;
  const float* Wp = W + (size_t)k0 * SD + n;
  #pragma unroll 4
  for (int kj = 0; kj < 64; ++kj) {
    int k = w + kj * 4;
    float wv = Wp[(size_t)k * SD];
    const float4* xr = reinterpret_cast<const float4*>(xt + k * 20);
    float4 a0 = xr[0], a1 = xr[1], a2 = xr[2], a3 = xr[3];
    acc[0] += wv * a0.x; acc[1] += wv * a0.y; acc[2] += wv * a0.z; acc[3] += wv * a0.w;
    acc[4] += wv * a1.x; acc[5] += wv * a1.y; acc[6] += wv * a1.z; acc[7] += wv * a1.w;
    acc[8] += wv * a2.x; acc[9] += wv * a2.y; acc[10] += wv * a2.z; acc[11] += wv * a2.w;
    acc[12] += wv * a3.x; acc[13] += wv * a3.y; acc[14] += wv * a3.z; acc[15] += wv * a3.w;
  }
  #pragma unroll
  for (int b2 = 0; b2 < 16; ++b2) red[w][lane][b2] = acc[b2];
  __syncthreads();
  for (int i = tid; i < 1024; i += 256) {
    int nn = i & 63, b2 = i >> 6;
    float r = red[0][nn][b2] + red[1][nn][b2] + red[2][nn][b2] + red[3][nn][b2];
    P[(size_t)(kt * 16 + b2) * SD + nt * 64 + nn] = r;
  }
}

// ============ layer-2 split-K GEMM, X = gelu(reduce(P1)+b1) fused in staging ==
// grid (12 nt, 6): ky<3 -> path A (np=9), else path B (np=27). K=768.
__global__ __launch_bounds__(256) void gemm2_fused(
    const float* __restrict__ P1A, const float* __restrict__ b1a,
    const float* __restrict__ W2A, float* __restrict__ P2A,
    const float* __restrict__ P1B, const float* __restrict__ b1b,
    const float* __restrict__ W2B, float* __restrict__ P2B) {
  int nt = blockIdx.x, ky = blockIdx.y;
  const float *P1, *bias, *W; float* P2; int kt, np;
  if (ky < 3) { P1 = P1A; bias = b1a; W = W2A; P2 = P2A; kt = ky; np = 9; }
  else { P1 = P1B; bias = b1b; W = W2B; P2 = P2B; kt = ky - 3; np = 27; }
  int k0 = kt * 256;
  __shared__ __align__(16) float xt[256 * 20];
  __shared__ float red[4][64][17];
  int tid = threadIdx.x;
  int kk = k0 + tid;
  #pragma unroll
  for (int b2 = 0; b2 < 16; ++b2) {
    float r = bias[kk];
    for (int kt2 = 0; kt2 < np; ++kt2)
      r += P1[(size_t)(kt2 * 16 + b2) * SD + kk];
    xt[tid * 20 + b2] = r * 0.5f * (1.f + erff(r * 0.70710678118654752f));
  }
  __syncthreads();
  int w = tid >> 6, lane = tid & 63;
  int n = nt * 64 + lane;
  float acc[16];
  #pragma unroll
  for (int b2 = 0; b2 < 16; ++b2) acc[b2] = 0.f;
  const float* Wp = W + (size_t)k0 * SD + n;
  #pragma unroll 4
  for (int kj = 0; kj < 64; ++kj) {
    int k = w + kj * 4;
    float wv = Wp[(size_t)k * SD];
    const float4* xr = reinterpret_cast<const float4*>(xt + k * 20);
    float4 a0 = xr[0], a1 = xr[1], a2 = xr[2], a3 = xr[3];
    acc[0] += wv * a0.x; acc[1] += wv * a0.y; acc[2] += wv * a0.z; acc[3] += wv * a0.w;
    acc[4] += wv * a1.x; acc[5] += wv * a1.y; acc[6] += wv * a1.z; acc[7] += wv * a1.w;
    acc[8] += wv * a2.x; acc[9] += wv * a2.y; acc[10] += wv * a2.z; acc[11] += wv * a2.w;
    acc[12] += wv * a3.x; acc[13] += wv * a3.y; acc[14] += wv * a3.z; acc[15] += wv * a3.w;
  }
  #pragma unroll
  for (int b2 = 0; b2 < 16; ++b2) red[w][lane][b2] = acc[b2];
  __syncthreads();
  for (int i = tid; i < 1024; i += 256) {
    int nn = i & 63, b2 = i >> 6;
    float r = red[0][nn][b2] + red[1][nn][b2] + red[2][nn][b2] + red[3][nn][b2];
    P2[(size_t)(kt * 16 + b2) * SD + nt * 64 + nn] = r;
  }
}

// ============ final: reduce + bias -> d_out ===================================
__global__ void final_reduce(const float* __restrict__ P2A, const float* __restrict__ b2a,
                             const float* __restrict__ P2B, const float* __restrict__ b2b,
                             float* __restrict__ out) {
  int y = blockIdx.y;
  const float* P = y ? P2B : P2A;
  const float* bias = y ? b2b : b2a;
  int j = blockIdx.x * 256 + threadIdx.x;  // < 12288
  float r = P[j] + P[12288 + j] + P[24576 + j] + bias[j % SD];
  int b = j / SD, nn = j - b * SD;
  out[b * 1536 + y * SD + nn] = r;
}

extern "C" void kernel_launch(void* const* d_in, const int* in_sizes, int n_in,
                              void* d_out, int out_size, void* d_ws, size_t ws_size,
                              hipStream_t stream) {
  const float* tokens = (const float*)d_in[0];
  const int* lengths  = (const int*)d_in[1];
  const float* q      = (const float*)d_in[2];
  const float* lns    = (const float*)d_in[3];
  const float* lnb    = (const float*)d_in[4];
  const float* w1a    = (const float*)d_in[5];
  const float* b1a    = (const float*)d_in[6];
  const float* w2a    = (const float*)d_in[7];
  const float* b2a    = (const float*)d_in[8];
  const float* w1b    = (const float*)d_in[9];
  const float* b1b    = (const float*)d_in[10];
  const float* w2b    = (const float*)d_in[11];
  const float* b2b    = (const float*)d_in[12];
  float* ws  = (float*)d_ws;
  float* out = (float*)d_out;

  float* ppool  = ws + OFF_PPOOL;
  float* pO     = ws + OFF_PO;
  float* pml    = ws + OFF_PML;
  float* ptrad  = ws + OFF_PTRAD;
  float* plearn = ws + OFF_PLEARN;
  float* p1a    = ws + OFF_P1A;
  float* p1b    = ws + OFF_P1B;
  float* p2a    = ws + OFF_P2A;
  float* p2b    = ws + OFF_P2B;

  k1_flash<<<dim3(32, 16), 256, 0, stream>>>(tokens, lengths, q, lns, lnb, ppool, pO, pml);
  k_combine<<<dim3(9, 16), 256, 0, stream>>>(ppool, pO, pml, tokens, lengths, ptrad, plearn);
  gemm_partial<<<dim3(12, 36), 256, 0, stream>>>(ptrad, w1a, 9, p1a, plearn, w1b, p1b);
  gemm2_fused<<<dim3(12, 6), 256, 0, stream>>>(p1a, b1a, w2a, p2a, p1b, b1b, w2b, p2b);
  final_reduce<<<dim3(48, 2), 256, 0, stream>>>(p2a, b2a, p2b, b2b, out);
}

// Round 4
// 238.942 us; speedup vs baseline: 1.5214x; 1.5214x over previous
//
#include <hip/hip_runtime.h>
#include <math.h>

#define SD 768
#define SB 16
#define SM 8
#define SS 2048
#define TOK_ROW 2049
#define NEG_INF (-__builtin_inff())

// ws layout (float offsets).
#define OFF_PPOOL   0          // 32*16*2304
#define OFF_PO      1179648    // 32*16*6144
#define OFF_PML     4325376    // 32*16*16
#define OFF_PTRAD   4333568    // 16*2304
#define OFF_PLEARN  4370432    // 16*6912
#define OFF_P1A     4481024    // 9*12288
#define OFF_P1B     4591616    // 27*12288
#define OFF_HA      4923392    // 12288
#define OFF_HB      4935680    // 12288
#define OFF_P2A     4947968    // 3*12288
#define OFF_P2B     4984832    // 3*12288

__device__ __forceinline__ int clen(int v) { return v < 1 ? 1 : (v > SS ? SS : v); }

// ============ K1: fused pool-partials + LN + scores + local-softmax + O_c =====
// grid (32 s-chunks, 16 b), 256 thr = 4 waves; wave w owns rows [c0+16w, +16)
__global__ __launch_bounds__(256, 2) void k1_flash(
    const float* __restrict__ tokens, const int* __restrict__ lengths,
    const float* __restrict__ q, const float* __restrict__ lns,
    const float* __restrict__ lnb, float* __restrict__ ppool,
    float* __restrict__ pO, float* __restrict__ pml) {
  int c = blockIdx.x, b = blockIdx.y;
  int len = clen(lengths[b]);
  int c0 = c * 64;
  if (c0 >= len) return;
  int tid = threadIdx.x, w = tid >> 6, lane = tid & 63;
  int mm = lane & 7;

  __shared__ float p_lds[4][16][8];       // 2 KB   scores -> probs
  __shared__ float pool_lds[4][3][SD];    // 36 KB
  __shared__ float O_lds[SM][SD];         // 24 KB
  __shared__ float mx_lds[8];

  // init p_lds to -inf (invalid rows contribute exp(-inf)=0)
  {
    float* pf = &p_lds[0][0][0];
    for (int i = tid; i < 512; i += 256) pf[i] = NEG_INF;
  }

  // ---- q setup: qs = q*scale (regs), qs1[m]=sum(qs), qb[m]=q.lnb ----
  float4 qr[8][3];
  float qs1sel, qbsel;
  {
    float4 l4[3], lb4[3];
    #pragma unroll
    for (int g = 0; g < 3; ++g) {
      l4[g] = *(const float4*)(lns + g * 256 + lane * 4);
      lb4[g] = *(const float4*)(lnb + g * 256 + lane * 4);
    }
    float qs1r[8], qbr[8];
    #pragma unroll
    for (int m = 0; m < 8; ++m) {
      float s1 = 0.f, sb = 0.f;
      #pragma unroll
      for (int g = 0; g < 3; ++g) {
        float4 qv = *(const float4*)(q + m * SD + g * 256 + lane * 4);
        float4 qs;
        qs.x = qv.x * l4[g].x; qs.y = qv.y * l4[g].y;
        qs.z = qv.z * l4[g].z; qs.w = qv.w * l4[g].w;
        qr[m][g] = qs;
        s1 += qs.x + qs.y + qs.z + qs.w;
        sb += qv.x * lb4[g].x + qv.y * lb4[g].y + qv.z * lb4[g].z + qv.w * lb4[g].w;
      }
      #pragma unroll
      for (int o = 32; o; o >>= 1) { s1 += __shfl_xor(s1, o, 64); sb += __shfl_xor(sb, o, 64); }
      qs1r[m] = s1; qbr[m] = sb;
    }
    qs1sel = qs1r[0]; qbsel = qbr[0];
    #pragma unroll
    for (int m = 1; m < 8; ++m) {
      qs1sel = (mm == m) ? qs1r[m] : qs1sel;
      qbsel = (mm == m) ? qbr[m] : qbsel;
    }
  }
  __syncthreads();  // p_lds init visible before phase-1 writes

  // ---- phase 1: pooling + LN stats + scores (software-pipelined loads) ----
  float psum[12], pmax[12], pmin[12];
  #pragma unroll
  for (int j = 0; j < 12; ++j) { psum[j] = 0.f; pmax[j] = NEG_INF; pmin[j] = -NEG_INF; }

  int srow = c0 + w * 16;
  int smax = len - srow; if (smax > 16) smax = 16; if (smax < 0) smax = 0;
  const float* xrow = tokens + ((size_t)b * TOK_ROW + 1 + srow) * SD;

  float4 nx0 = {}, nx1 = {}, nx2 = {};
  if (smax > 0) {
    nx0 = *(const float4*)(xrow + lane * 4);
    nx1 = *(const float4*)(xrow + 256 + lane * 4);
    nx2 = *(const float4*)(xrow + 512 + lane * 4);
  }
  for (int i = 0; i < smax; ++i) {
    float4 x0 = nx0, x1 = nx1, x2 = nx2;
    if (i + 1 < smax) {
      const float* xq = xrow + (size_t)(i + 1) * SD;
      nx0 = *(const float4*)(xq + lane * 4);
      nx1 = *(const float4*)(xq + 256 + lane * 4);
      nx2 = *(const float4*)(xq + 512 + lane * 4);
    }
    float xv[12] = {x0.x, x0.y, x0.z, x0.w, x1.x, x1.y, x1.z, x1.w,
                    x2.x, x2.y, x2.z, x2.w};
    float s1 = 0.f, s2 = 0.f;
    #pragma unroll
    for (int j = 0; j < 12; ++j) {
      float v = xv[j];
      psum[j] += v;
      pmax[j] = fmaxf(pmax[j], v);
      pmin[j] = fminf(pmin[j], v);
      s1 += v;
      s2 += v * v;
    }
    float d[8];
    #pragma unroll
    for (int m = 0; m < 8; ++m) {
      float4 a0 = qr[m][0], a1 = qr[m][1], a2 = qr[m][2];
      d[m] = a0.x * xv[0] + a0.y * xv[1] + a0.z * xv[2] + a0.w * xv[3]
           + a1.x * xv[4] + a1.y * xv[5] + a1.z * xv[6] + a1.w * xv[7]
           + a2.x * xv[8] + a2.y * xv[9] + a2.z * xv[10] + a2.w * xv[11];
    }
    // reduce: d butterfly {1,2,4}, select by lane&7, then {8,16,32} with s1,s2
    #pragma unroll
    for (int o = 1; o <= 4; o <<= 1)
      #pragma unroll
      for (int m = 0; m < 8; ++m) d[m] += __shfl_xor(d[m], o, 64);
    float u = d[0];
    #pragma unroll
    for (int m = 1; m < 8; ++m) u = (mm == m) ? d[m] : u;
    #pragma unroll
    for (int o = 8; o <= 32; o <<= 1) {
      u += __shfl_xor(u, o, 64);
      s1 += __shfl_xor(s1, o, 64);
      s2 += __shfl_xor(s2, o, 64);
    }
    #pragma unroll
    for (int o = 1; o <= 4; o <<= 1) { s1 += __shfl_xor(s1, o, 64); s2 += __shfl_xor(s2, o, 64); }
    float mu = s1 * (1.f / 768.f);
    float var = s2 * (1.f / 768.f) - mu * mu;
    float rstd = rsqrtf(var + 1e-5f);
    float sc = (rstd * u - rstd * mu * qs1sel + qbsel) * 0.03608439182435161f;
    if (lane < 8) p_lds[w][i][lane] = sc;
  }

  // pool partials -> LDS
  #pragma unroll
  for (int g = 0; g < 3; ++g) {
    int dd = g * 256 + lane * 4;
    *(float4*)&pool_lds[w][0][dd] = make_float4(psum[g*4], psum[g*4+1], psum[g*4+2], psum[g*4+3]);
    *(float4*)&pool_lds[w][1][dd] = make_float4(pmax[g*4], pmax[g*4+1], pmax[g*4+2], pmax[g*4+3]);
    *(float4*)&pool_lds[w][2][dd] = make_float4(pmin[g*4], pmin[g*4+1], pmin[g*4+2], pmin[g*4+3]);
  }
  __syncthreads();

  // ---- chunk-local softmax on p_lds ----
  float* pf = &p_lds[0][0][0];
  if (tid < 8) {
    float mxv = NEG_INF;
    for (int r = 0; r < 64; ++r) mxv = fmaxf(mxv, pf[r * 8 + tid]);
    mx_lds[tid] = mxv;
  }
  __syncthreads();
  for (int e = tid; e < 512; e += 256) {
    int m = e & 7;
    pf[e] = __expf(pf[e] - mx_lds[m]);
  }
  __syncthreads();
  if (tid < 8) {
    float lv = 0.f;
    for (int r = 0; r < 64; ++r) lv += pf[r * 8 + tid];
    size_t base = (size_t)(c * SB + b) * 16;
    pml[base + tid] = mx_lds[tid];
    pml[base + 8 + tid] = lv;
  }

  // ---- phase 2: O_w[m][d] = sum_rows p * x  (x re-read, L1/L2-hot, pipelined) ----
  float O[8][12];
  #pragma unroll
  for (int m = 0; m < 8; ++m)
    #pragma unroll
    for (int j = 0; j < 12; ++j) O[m][j] = 0.f;
  if (smax > 0) {
    nx0 = *(const float4*)(xrow + lane * 4);
    nx1 = *(const float4*)(xrow + 256 + lane * 4);
    nx2 = *(const float4*)(xrow + 512 + lane * 4);
  }
  for (int i = 0; i < smax; ++i) {
    float4 x0 = nx0, x1 = nx1, x2 = nx2;
    if (i + 1 < smax) {
      const float* xq = xrow + (size_t)(i + 1) * SD;
      nx0 = *(const float4*)(xq + lane * 4);
      nx1 = *(const float4*)(xq + 256 + lane * 4);
      nx2 = *(const float4*)(xq + 512 + lane * 4);
    }
    float xv[12] = {x0.x, x0.y, x0.z, x0.w, x1.x, x1.y, x1.z, x1.w,
                    x2.x, x2.y, x2.z, x2.w};
    const float4* pr = (const float4*)&p_lds[w][i][0];
    float4 pa = pr[0], pb = pr[1];
    float pm[8] = {pa.x, pa.y, pa.z, pa.w, pb.x, pb.y, pb.z, pb.w};
    #pragma unroll
    for (int m = 0; m < 8; ++m)
      #pragma unroll
      for (int j = 0; j < 12; ++j) O[m][j] += pm[m] * xv[j];
  }
  // accumulate O across waves in LDS
  #pragma unroll
  for (int r = 0; r < 4; ++r) {
    if (w == r) {
      #pragma unroll
      for (int m = 0; m < 8; ++m)
        #pragma unroll
        for (int g = 0; g < 3; ++g) {
          int dd = g * 256 + lane * 4;
          float4 mine = make_float4(O[m][g*4], O[m][g*4+1], O[m][g*4+2], O[m][g*4+3]);
          if (r == 0) {
            *(float4*)&O_lds[m][dd] = mine;
          } else {
            float4 cur = *(float4*)&O_lds[m][dd];
            cur.x += mine.x; cur.y += mine.y; cur.z += mine.z; cur.w += mine.w;
            *(float4*)&O_lds[m][dd] = cur;
          }
        }
    }
    __syncthreads();
  }

  // ---- writeout ----
  size_t obase = (size_t)(c * SB + b) * 6144;
  const float* of = &O_lds[0][0];
  for (int j = tid * 4; j < 6144; j += 1024)
    *(float4*)&pO[obase + j] = *(const float4*)&of[j];

  size_t pbase = (size_t)(c * SB + b) * 2304;
  for (int j4 = tid * 4; j4 < 2304; j4 += 1024) {
    int stat = j4 / SD, dd = j4 - stat * SD;
    float4 v0 = *(float4*)&pool_lds[0][stat][dd];
    float4 v1 = *(float4*)&pool_lds[1][stat][dd];
    float4 v2 = *(float4*)&pool_lds[2][stat][dd];
    float4 v3 = *(float4*)&pool_lds[3][stat][dd];
    float4 r;
    if (stat == 0) {
      r.x = v0.x + v1.x + v2.x + v3.x; r.y = v0.y + v1.y + v2.y + v3.y;
      r.z = v0.z + v1.z + v2.z + v3.z; r.w = v0.w + v1.w + v2.w + v3.w;
    } else if (stat == 1) {
      r.x = fmaxf(fmaxf(v0.x, v1.x), fmaxf(v2.x, v3.x));
      r.y = fmaxf(fmaxf(v0.y, v1.y), fmaxf(v2.y, v3.y));
      r.z = fmaxf(fmaxf(v0.z, v1.z), fmaxf(v2.z, v3.z));
      r.w = fmaxf(fmaxf(v0.w, v1.w), fmaxf(v2.w, v3.w));
    } else {
      r.x = fminf(fminf(v0.x, v1.x), fminf(v2.x, v3.x));
      r.y = fminf(fminf(v0.y, v1.y), fminf(v2.y, v3.y));
      r.z = fminf(fminf(v0.z, v1.z), fminf(v2.z, v3.z));
      r.w = fminf(fminf(v0.w, v1.w), fminf(v2.w, v3.w));
    }
    *(float4*)&ppool[pbase + j4] = r;
  }
}

// ============ combine: flash-rescale O + pool-reduce + clf -> ptrad, plearn ===
__global__ void k_combine(const float* __restrict__ ppool, const float* __restrict__ pO,
                          const float* __restrict__ pml, const float* __restrict__ tokens,
                          const int* __restrict__ lengths,
                          float* __restrict__ ptrad, float* __restrict__ plearn) {
  int tile = blockIdx.x, b = blockIdx.y;
  int len = clen(lengths[b]);
  int nv = (len + 63) >> 6;
  int tid = threadIdx.x;
  __shared__ float pml_lds[32][16];
  __shared__ float e_lds[32][8];
  __shared__ float Linv_lds[8];
  for (int t = tid; t < nv * 16; t += 256) {
    int cc = t >> 4, j = t & 15;
    pml_lds[cc][j] = pml[(size_t)(cc * SB + b) * 16 + j];
  }
  __syncthreads();
  if (tid < 8) {
    float M = NEG_INF;
    for (int cc = 0; cc < nv; ++cc) M = fmaxf(M, pml_lds[cc][tid]);
    float L = 0.f;
    for (int cc = 0; cc < nv; ++cc) {
      float e = __expf(pml_lds[cc][tid] - M);
      e_lds[cc][tid] = e;
      L += e * pml_lds[cc][8 + tid];
    }
    Linv_lds[tid] = 1.f / L;
  }
  __syncthreads();
  #pragma unroll
  for (int k = 0; k < 4; ++k) {
    int jj = tile * 1024 + k * 256 + tid;
    if (jj < 2304) {
      int stat = jj / SD;
      const float* pp = ppool + jj + (size_t)b * 2304;
      if (stat == 0) {
        float a0 = 0.f, a1 = 0.f, a2 = 0.f, a3 = 0.f;
        int cc = 0;
        for (; cc + 4 <= nv; cc += 4) {
          a0 += pp[(size_t)(cc    ) * SB * 2304];
          a1 += pp[(size_t)(cc + 1) * SB * 2304];
          a2 += pp[(size_t)(cc + 2) * SB * 2304];
          a3 += pp[(size_t)(cc + 3) * SB * 2304];
        }
        for (; cc < nv; ++cc) a0 += pp[(size_t)cc * SB * 2304];
        ptrad[b * 2304 + jj] = ((a0 + a1) + (a2 + a3)) / (float)len;
      } else if (stat == 1) {
        float a0 = NEG_INF, a1 = NEG_INF, a2 = NEG_INF, a3 = NEG_INF;
        int cc = 0;
        for (; cc + 4 <= nv; cc += 4) {
          a0 = fmaxf(a0, pp[(size_t)(cc    ) * SB * 2304]);
          a1 = fmaxf(a1, pp[(size_t)(cc + 1) * SB * 2304]);
          a2 = fmaxf(a2, pp[(size_t)(cc + 2) * SB * 2304]);
          a3 = fmaxf(a3, pp[(size_t)(cc + 3) * SB * 2304]);
        }
        for (; cc < nv; ++cc) a0 = fmaxf(a0, pp[(size_t)cc * SB * 2304]);
        ptrad[b * 2304 + jj] = fmaxf(fmaxf(a0, a1), fmaxf(a2, a3));
      } else {
        float a0 = -NEG_INF, a1 = -NEG_INF, a2 = -NEG_INF, a3 = -NEG_INF;
        int cc = 0;
        for (; cc + 4 <= nv; cc += 4) {
          a0 = fminf(a0, pp[(size_t)(cc    ) * SB * 2304]);
          a1 = fminf(a1, pp[(size_t)(cc + 1) * SB * 2304]);
          a2 = fminf(a2, pp[(size_t)(cc + 2) * SB * 2304]);
          a3 = fminf(a3, pp[(size_t)(cc + 3) * SB * 2304]);
        }
        for (; cc < nv; ++cc) a0 = fminf(a0, pp[(size_t)cc * SB * 2304]);
        ptrad[b * 2304 + jj] = fminf(fminf(a0, a1), fminf(a2, a3));
      }
    } else if (jj < 8448) {
      int t = jj - 2304;
      int m = t / SD;
      const float* po = pO + t + (size_t)b * 6144;
      float a0 = 0.f, a1 = 0.f, a2 = 0.f, a3 = 0.f;
      int cc = 0;
      for (; cc + 4 <= nv; cc += 4) {
        a0 += po[(size_t)(cc    ) * SB * 6144] * e_lds[cc    ][m];
        a1 += po[(size_t)(cc + 1) * SB * 6144] * e_lds[cc + 1][m];
        a2 += po[(size_t)(cc + 2) * SB * 6144] * e_lds[cc + 2][m];
        a3 += po[(size_t)(cc + 3) * SB * 6144] * e_lds[cc + 3][m];
      }
      for (; cc < nv; ++cc) a0 += po[(size_t)cc * SB * 6144] * e_lds[cc][m];
      plearn[b * 6912 + t] = ((a0 + a1) + (a2 + a3)) * Linv_lds[m];
    } else {
      int dd = jj - 8448;
      plearn[b * 6912 + 6144 + dd] = tokens[(size_t)b * TOK_ROW * SD + dd];
    }
  }
}

// ============ split-K GEMM partial: (16 x K) @ (K x 768) ======================
__global__ __launch_bounds__(256) void gemm_partial(
    const float* __restrict__ XA, const float* __restrict__ WA, int ktA, float* __restrict__ PA,
    const float* __restrict__ XB, const float* __restrict__ WB, float* __restrict__ PB) {
  int nt = blockIdx.x, ky = blockIdx.y;
  const float *X, *W; float* P; int kt, ktN;
  if (ky < ktA) { X = XA; W = WA; P = PA; kt = ky; ktN = ktA; }
  else { X = XB; W = WB; P = PB; kt = ky - ktA; ktN = gridDim.y - ktA; }
  int K = ktN * 256;
  int k0 = kt * 256;
  __shared__ __align__(16) float xt[256 * 20];
  __shared__ float red[4][64][17];
  int tid = threadIdx.x;
  #pragma unroll
  for (int b2 = 0; b2 < 16; ++b2) xt[tid * 20 + b2] = X[b2 * K + k0 + tid];
  __syncthreads();
  int w = tid >> 6, lane = tid & 63;
  int n = nt * 64 + lane;
  float acc[16];
  #pragma unroll
  for (int b2 = 0; b2 < 16; ++b2) acc[b2] = 0.f;
  const float* Wp = W + (size_t)k0 * SD + n;
  #pragma unroll 8
  for (int kj = 0; kj < 64; ++kj) {
    int k = w + kj * 4;
    float wv = Wp[(size_t)k * SD];
    const float4* xr = reinterpret_cast<const float4*>(xt + k * 20);
    float4 a0 = xr[0], a1 = xr[1], a2 = xr[2], a3 = xr[3];
    acc[0] += wv * a0.x; acc[1] += wv * a0.y; acc[2] += wv * a0.z; acc[3] += wv * a0.w;
    acc[4] += wv * a1.x; acc[5] += wv * a1.y; acc[6] += wv * a1.z; acc[7] += wv * a1.w;
    acc[8] += wv * a2.x; acc[9] += wv * a2.y; acc[10] += wv * a2.z; acc[11] += wv * a2.w;
    acc[12] += wv * a3.x; acc[13] += wv * a3.y; acc[14] += wv * a3.z; acc[15] += wv * a3.w;
  }
  #pragma unroll
  for (int b2 = 0; b2 < 16; ++b2) red[w][lane][b2] = acc[b2];
  __syncthreads();
  for (int i = tid; i < 1024; i += 256) {
    int nn = i & 63, b2 = i >> 6;
    float r = red[0][nn][b2] + red[1][nn][b2] + red[2][nn][b2] + red[3][nn][b2];
    P[(size_t)(kt * 16 + b2) * SD + nt * 64 + nn] = r;
  }
}

// ============ reduce + bias + exact GELU (compile-time trip counts) ===========
__global__ void gelu_reduce(const float* __restrict__ PA, const float* __restrict__ b1a,
                            float* __restrict__ HA, const float* __restrict__ PB,
                            const float* __restrict__ b1b, float* __restrict__ HB) {
  int y = blockIdx.y;
  int j = blockIdx.x * 256 + threadIdx.x;  // < 12288
  float r;
  if (y == 0) {
    r = b1a[j % SD];
    #pragma unroll
    for (int kt = 0; kt < 9; ++kt) r += PA[kt * 12288 + j];
    HA[j] = r * 0.5f * (1.f + erff(r * 0.70710678118654752f));
  } else {
    r = b1b[j % SD];
    #pragma unroll
    for (int kt = 0; kt < 27; ++kt) r += PB[kt * 12288 + j];
    HB[j] = r * 0.5f * (1.f + erff(r * 0.70710678118654752f));
  }
}

// ============ final: reduce + bias -> d_out ===================================
__global__ void final_reduce(const float* __restrict__ P2A, const float* __restrict__ b2a,
                             const float* __restrict__ P2B, const float* __restrict__ b2b,
                             float* __restrict__ out) {
  int y = blockIdx.y;
  const float* P = y ? P2B : P2A;
  const float* bias = y ? b2b : b2a;
  int j = blockIdx.x * 256 + threadIdx.x;  // < 12288
  float r = P[j] + P[12288 + j] + P[24576 + j] + bias[j % SD];
  int b = j / SD, nn = j - b * SD;
  out[b * 1536 + y * SD + nn] = r;
}

extern "C" void kernel_launch(void* const* d_in, const int* in_sizes, int n_in,
                              void* d_out, int out_size, void* d_ws, size_t ws_size,
                              hipStream_t stream) {
  const float* tokens = (const float*)d_in[0];
  const int* lengths  = (const int*)d_in[1];
  const float* q      = (const float*)d_in[2];
  const float* lns    = (const float*)d_in[3];
  const float* lnb    = (const float*)d_in[4];
  const float* w1a    = (const float*)d_in[5];
  const float* b1a    = (const float*)d_in[6];
  const float* w2a    = (const float*)d_in[7];
  const float* b2a    = (const float*)d_in[8];
  const float* w1b    = (const float*)d_in[9];
  const float* b1b    = (const float*)d_in[10];
  const float* w2b    = (const float*)d_in[11];
  const float* b2b    = (const float*)d_in[12];
  float* ws  = (float*)d_ws;
  float* out = (float*)d_out;

  float* ppool  = ws + OFF_PPOOL;
  float* pO     = ws + OFF_PO;
  float* pml    = ws + OFF_PML;
  float* ptrad  = ws + OFF_PTRAD;
  float* plearn = ws + OFF_PLEARN;
  float* p1a    = ws + OFF_P1A;
  float* p1b    = ws + OFF_P1B;
  float* ha     = ws + OFF_HA;
  float* hb     = ws + OFF_HB;
  float* p2a    = ws + OFF_P2A;
  float* p2b    = ws + OFF_P2B;

  k1_flash<<<dim3(32, 16), 256, 0, stream>>>(tokens, lengths, q, lns, lnb, ppool, pO, pml);
  k_combine<<<dim3(9, 16), 256, 0, stream>>>(ppool, pO, pml, tokens, lengths, ptrad, plearn);
  gemm_partial<<<dim3(12, 36), 256, 0, stream>>>(ptrad, w1a, 9, p1a, plearn, w1b, p1b);
  gelu_reduce<<<dim3(48, 2), 256, 0, stream>>>(p1a, b1a, ha, p1b, b1b, hb);
  gemm_partial<<<dim3(12, 6), 256, 0, stream>>>(ha, w2a, 3, p2a, hb, w2b, p2b);
  final_reduce<<<dim3(48, 2), 256, 0, stream>>>(p2a, b2a, p2b, b2b, out);
}

// Round 5
// 230.646 us; speedup vs baseline: 1.5762x; 1.0360x over previous
//
#include <hip/hip_runtime.h>
#include <math.h>

#define SD 768
#define SB 16
#define SM 8
#define SS 2048
#define TOK_ROW 2049
#define NEG_INF (-__builtin_inff())

// ws layout (float offsets). Total 5,537,792 floats = 22.2 MB.
#define OFF_PPOOL   0          // 32*16*2304
#define OFF_PO      1179648    // 32*16*6144
#define OFF_PML     4325376    // 512*16
#define OFF_PTRAD   4333568    // 16*2304
#define OFF_PLEARN  4370432    // 16*6912
#define OFF_P1A     4481024    // 18*12288
#define OFF_P1B     4702208    // 54*12288
#define OFF_HA      5365760    // 12288
#define OFF_HB      5378048    // 12288
#define OFF_P2A     5390336    // 6*12288
#define OFF_P2B     5464064    // 6*12288

__device__ __forceinline__ int clen(int v) { return v < 1 ? 1 : (v > SS ? SS : v); }

// ============ K1: fused pool-partials + LN + scores + local-softmax + O_c =====
// grid (32 s-chunks, 16 b), 256 thr = 4 waves; wave w owns rows [c0+16w, +16)
__global__ __launch_bounds__(256, 2) void k1_flash(
    const float* __restrict__ tokens, const int* __restrict__ lengths,
    const float* __restrict__ q, const float* __restrict__ lns,
    const float* __restrict__ lnb, float* __restrict__ ppool,
    float* __restrict__ pO, float* __restrict__ pml) {
  int c = blockIdx.x, b = blockIdx.y;
  int len = clen(lengths[b]);
  int c0 = c * 64;
  if (c0 >= len) return;
  int tid = threadIdx.x, w = tid >> 6, lane = tid & 63;
  int mm = lane & 7;

  __shared__ float p_lds[4][16][8];       // 2 KB   scores -> probs
  __shared__ float pool_lds[4][3][SD];    // 36 KB
  __shared__ float O_lds[SM][SD];         // 24 KB
  __shared__ float mx_lds[8];

  // init p_lds to -inf (invalid rows contribute exp(-inf)=0)
  {
    float* pf = &p_lds[0][0][0];
    for (int i = tid; i < 512; i += 256) pf[i] = NEG_INF;
  }

  // ---- q setup: qs = q*scale (regs), qs1[m]=sum(qs), qb[m]=q.lnb ----
  float4 qr[8][3];
  float qs1sel, qbsel;
  {
    float4 l4[3], lb4[3];
    #pragma unroll
    for (int g = 0; g < 3; ++g) {
      l4[g] = *(const float4*)(lns + g * 256 + lane * 4);
      lb4[g] = *(const float4*)(lnb + g * 256 + lane * 4);
    }
    float qs1r[8], qbr[8];
    #pragma unroll
    for (int m = 0; m < 8; ++m) {
      float s1 = 0.f, sb = 0.f;
      #pragma unroll
      for (int g = 0; g < 3; ++g) {
        float4 qv = *(const float4*)(q + m * SD + g * 256 + lane * 4);
        float4 qs;
        qs.x = qv.x * l4[g].x; qs.y = qv.y * l4[g].y;
        qs.z = qv.z * l4[g].z; qs.w = qv.w * l4[g].w;
        qr[m][g] = qs;
        s1 += qs.x + qs.y + qs.z + qs.w;
        sb += qv.x * lb4[g].x + qv.y * lb4[g].y + qv.z * lb4[g].z + qv.w * lb4[g].w;
      }
      #pragma unroll
      for (int o = 32; o; o >>= 1) { s1 += __shfl_xor(s1, o, 64); sb += __shfl_xor(sb, o, 64); }
      qs1r[m] = s1; qbr[m] = sb;
    }
    qs1sel = qs1r[0]; qbsel = qbr[0];
    #pragma unroll
    for (int m = 1; m < 8; ++m) {
      qs1sel = (mm == m) ? qs1r[m] : qs1sel;
      qbsel = (mm == m) ? qbr[m] : qbsel;
    }
  }
  __syncthreads();  // p_lds init visible before phase-1 writes

  // ---- phase 1: pooling + LN stats + scores (software-pipelined loads) ----
  float psum[12], pmax[12], pmin[12];
  #pragma unroll
  for (int j = 0; j < 12; ++j) { psum[j] = 0.f; pmax[j] = NEG_INF; pmin[j] = -NEG_INF; }

  int srow = c0 + w * 16;
  int smax = len - srow; if (smax > 16) smax = 16; if (smax < 0) smax = 0;
  const float* xrow = tokens + ((size_t)b * TOK_ROW + 1 + srow) * SD;

  float4 nx0 = {}, nx1 = {}, nx2 = {};
  if (smax > 0) {
    nx0 = *(const float4*)(xrow + lane * 4);
    nx1 = *(const float4*)(xrow + 256 + lane * 4);
    nx2 = *(const float4*)(xrow + 512 + lane * 4);
  }
  for (int i = 0; i < smax; ++i) {
    float4 x0 = nx0, x1 = nx1, x2 = nx2;
    if (i + 1 < smax) {
      const float* xq = xrow + (size_t)(i + 1) * SD;
      nx0 = *(const float4*)(xq + lane * 4);
      nx1 = *(const float4*)(xq + 256 + lane * 4);
      nx2 = *(const float4*)(xq + 512 + lane * 4);
    }
    float xv[12] = {x0.x, x0.y, x0.z, x0.w, x1.x, x1.y, x1.z, x1.w,
                    x2.x, x2.y, x2.z, x2.w};
    float s1 = 0.f, s2 = 0.f;
    #pragma unroll
    for (int j = 0; j < 12; ++j) {
      float v = xv[j];
      psum[j] += v;
      pmax[j] = fmaxf(pmax[j], v);
      pmin[j] = fminf(pmin[j], v);
      s1 += v;
      s2 += v * v;
    }
    float d[8];
    #pragma unroll
    for (int m = 0; m < 8; ++m) {
      float4 a0 = qr[m][0], a1 = qr[m][1], a2 = qr[m][2];
      d[m] = a0.x * xv[0] + a0.y * xv[1] + a0.z * xv[2] + a0.w * xv[3]
           + a1.x * xv[4] + a1.y * xv[5] + a1.z * xv[6] + a1.w * xv[7]
           + a2.x * xv[8] + a2.y * xv[9] + a2.z * xv[10] + a2.w * xv[11];
    }
    // reduce: d butterfly {1,2,4}, select by lane&7, then {8,16,32} with s1,s2
    #pragma unroll
    for (int o = 1; o <= 4; o <<= 1)
      #pragma unroll
      for (int m = 0; m < 8; ++m) d[m] += __shfl_xor(d[m], o, 64);
    float u = d[0];
    #pragma unroll
    for (int m = 1; m < 8; ++m) u = (mm == m) ? d[m] : u;
    #pragma unroll
    for (int o = 8; o <= 32; o <<= 1) {
      u += __shfl_xor(u, o, 64);
      s1 += __shfl_xor(s1, o, 64);
      s2 += __shfl_xor(s2, o, 64);
    }
    #pragma unroll
    for (int o = 1; o <= 4; o <<= 1) { s1 += __shfl_xor(s1, o, 64); s2 += __shfl_xor(s2, o, 64); }
    float mu = s1 * (1.f / 768.f);
    float var = s2 * (1.f / 768.f) - mu * mu;
    float rstd = rsqrtf(var + 1e-5f);
    float sc = (rstd * u - rstd * mu * qs1sel + qbsel) * 0.03608439182435161f;
    if (lane < 8) p_lds[w][i][lane] = sc;
  }

  // pool partials -> LDS
  #pragma unroll
  for (int g = 0; g < 3; ++g) {
    int dd = g * 256 + lane * 4;
    *(float4*)&pool_lds[w][0][dd] = make_float4(psum[g*4], psum[g*4+1], psum[g*4+2], psum[g*4+3]);
    *(float4*)&pool_lds[w][1][dd] = make_float4(pmax[g*4], pmax[g*4+1], pmax[g*4+2], pmax[g*4+3]);
    *(float4*)&pool_lds[w][2][dd] = make_float4(pmin[g*4], pmin[g*4+1], pmin[g*4+2], pmin[g*4+3]);
  }
  __syncthreads();

  // ---- chunk-local softmax on p_lds ----
  float* pf = &p_lds[0][0][0];
  if (tid < 8) {
    float mxv = NEG_INF;
    for (int r = 0; r < 64; ++r) mxv = fmaxf(mxv, pf[r * 8 + tid]);
    mx_lds[tid] = mxv;
  }
  __syncthreads();
  for (int e = tid; e < 512; e += 256) {
    int m = e & 7;
    pf[e] = __expf(pf[e] - mx_lds[m]);
  }
  __syncthreads();
  if (tid < 8) {
    float lv = 0.f;
    for (int r = 0; r < 64; ++r) lv += pf[r * 8 + tid];
    size_t base = (size_t)(c * SB + b) * 16;
    pml[base + tid] = mx_lds[tid];
    pml[base + 8 + tid] = lv;
  }

  // ---- phase 2: O_w[m][d] = sum_rows p * x  (x re-read L2/L3-hot, 2-deep pipe) ----
  float O[8][12];
  #pragma unroll
  for (int m = 0; m < 8; ++m)
    #pragma unroll
    for (int j = 0; j < 12; ++j) O[m][j] = 0.f;
  float4 a0v = {}, a1v = {}, a2v = {}, b0v = {}, b1v = {}, b2v = {};
  if (smax > 0) {
    a0v = *(const float4*)(xrow + lane * 4);
    a1v = *(const float4*)(xrow + 256 + lane * 4);
    a2v = *(const float4*)(xrow + 512 + lane * 4);
  }
  if (smax > 1) {
    const float* xq = xrow + SD;
    b0v = *(const float4*)(xq + lane * 4);
    b1v = *(const float4*)(xq + 256 + lane * 4);
    b2v = *(const float4*)(xq + 512 + lane * 4);
  }
  for (int i = 0; i < smax; ++i) {
    float4 x0 = a0v, x1 = a1v, x2 = a2v;
    a0v = b0v; a1v = b1v; a2v = b2v;
    if (i + 2 < smax) {
      const float* xq = xrow + (size_t)(i + 2) * SD;
      b0v = *(const float4*)(xq + lane * 4);
      b1v = *(const float4*)(xq + 256 + lane * 4);
      b2v = *(const float4*)(xq + 512 + lane * 4);
    }
    float xv[12] = {x0.x, x0.y, x0.z, x0.w, x1.x, x1.y, x1.z, x1.w,
                    x2.x, x2.y, x2.z, x2.w};
    const float4* pr = (const float4*)&p_lds[w][i][0];
    float4 pa = pr[0], pb = pr[1];
    float pm[8] = {pa.x, pa.y, pa.z, pa.w, pb.x, pb.y, pb.z, pb.w};
    #pragma unroll
    for (int m = 0; m < 8; ++m)
      #pragma unroll
      for (int j = 0; j < 12; ++j) O[m][j] += pm[m] * xv[j];
  }
  // accumulate O across waves in LDS
  #pragma unroll
  for (int r = 0; r < 4; ++r) {
    if (w == r) {
      #pragma unroll
      for (int m = 0; m < 8; ++m)
        #pragma unroll
        for (int g = 0; g < 3; ++g) {
          int dd = g * 256 + lane * 4;
          float4 mine = make_float4(O[m][g*4], O[m][g*4+1], O[m][g*4+2], O[m][g*4+3]);
          if (r == 0) {
            *(float4*)&O_lds[m][dd] = mine;
          } else {
            float4 cur = *(float4*)&O_lds[m][dd];
            cur.x += mine.x; cur.y += mine.y; cur.z += mine.z; cur.w += mine.w;
            *(float4*)&O_lds[m][dd] = cur;
          }
        }
    }
    __syncthreads();
  }

  // ---- writeout ----
  size_t obase = (size_t)(c * SB + b) * 6144;
  const float* of = &O_lds[0][0];
  for (int j = tid * 4; j < 6144; j += 1024)
    *(float4*)&pO[obase + j] = *(const float4*)&of[j];

  size_t pbase = (size_t)(c * SB + b) * 2304;
  for (int j4 = tid * 4; j4 < 2304; j4 += 1024) {
    int stat = j4 / SD, dd = j4 - stat * SD;
    float4 v0 = *(float4*)&pool_lds[0][stat][dd];
    float4 v1 = *(float4*)&pool_lds[1][stat][dd];
    float4 v2 = *(float4*)&pool_lds[2][stat][dd];
    float4 v3 = *(float4*)&pool_lds[3][stat][dd];
    float4 r;
    if (stat == 0) {
      r.x = v0.x + v1.x + v2.x + v3.x; r.y = v0.y + v1.y + v2.y + v3.y;
      r.z = v0.z + v1.z + v2.z + v3.z; r.w = v0.w + v1.w + v2.w + v3.w;
    } else if (stat == 1) {
      r.x = fmaxf(fmaxf(v0.x, v1.x), fmaxf(v2.x, v3.x));
      r.y = fmaxf(fmaxf(v0.y, v1.y), fmaxf(v2.y, v3.y));
      r.z = fmaxf(fmaxf(v0.z, v1.z), fmaxf(v2.z, v3.z));
      r.w = fmaxf(fmaxf(v0.w, v1.w), fmaxf(v2.w, v3.w));
    } else {
      r.x = fminf(fminf(v0.x, v1.x), fminf(v2.x, v3.x));
      r.y = fminf(fminf(v0.y, v1.y), fminf(v2.y, v3.y));
      r.z = fminf(fminf(v0.z, v1.z), fminf(v2.z, v3.z));
      r.w = fminf(fminf(v0.w, v1.w), fminf(v2.w, v3.w));
    }
    *(float4*)&ppool[pbase + j4] = r;
  }
}

// ============ combine: flash-rescale O + pool-reduce + clf -> ptrad, plearn ===
__global__ void k_combine(const float* __restrict__ ppool, const float* __restrict__ pO,
                          const float* __restrict__ pml, const float* __restrict__ tokens,
                          const int* __restrict__ lengths,
                          float* __restrict__ ptrad, float* __restrict__ plearn) {
  int tile = blockIdx.x, b = blockIdx.y;
  int len = clen(lengths[b]);
  int nv = (len + 63) >> 6;
  int tid = threadIdx.x;
  __shared__ float pml_lds[32][16];
  __shared__ float e_lds[32][8];
  __shared__ float Linv_lds[8];
  for (int t = tid; t < nv * 16; t += 256) {
    int cc = t >> 4, j = t & 15;
    pml_lds[cc][j] = pml[(size_t)(cc * SB + b) * 16 + j];
  }
  __syncthreads();
  if (tid < 8) {
    float M = NEG_INF;
    for (int cc = 0; cc < nv; ++cc) M = fmaxf(M, pml_lds[cc][tid]);
    float L = 0.f;
    for (int cc = 0; cc < nv; ++cc) {
      float e = __expf(pml_lds[cc][tid] - M);
      e_lds[cc][tid] = e;
      L += e * pml_lds[cc][8 + tid];
    }
    Linv_lds[tid] = 1.f / L;
  }
  __syncthreads();
  #pragma unroll
  for (int k = 0; k < 4; ++k) {
    int jj = tile * 1024 + k * 256 + tid;
    if (jj < 2304) {
      int stat = jj / SD;
      const float* pp = ppool + jj + (size_t)b * 2304;
      if (stat == 0) {
        float a0 = 0.f, a1 = 0.f, a2 = 0.f, a3 = 0.f;
        int cc = 0;
        for (; cc + 4 <= nv; cc += 4) {
          a0 += pp[(size_t)(cc    ) * SB * 2304];
          a1 += pp[(size_t)(cc + 1) * SB * 2304];
          a2 += pp[(size_t)(cc + 2) * SB * 2304];
          a3 += pp[(size_t)(cc + 3) * SB * 2304];
        }
        for (; cc < nv; ++cc) a0 += pp[(size_t)cc * SB * 2304];
        ptrad[b * 2304 + jj] = ((a0 + a1) + (a2 + a3)) / (float)len;
      } else if (stat == 1) {
        float a0 = NEG_INF, a1 = NEG_INF, a2 = NEG_INF, a3 = NEG_INF;
        int cc = 0;
        for (; cc + 4 <= nv; cc += 4) {
          a0 = fmaxf(a0, pp[(size_t)(cc    ) * SB * 2304]);
          a1 = fmaxf(a1, pp[(size_t)(cc + 1) * SB * 2304]);
          a2 = fmaxf(a2, pp[(size_t)(cc + 2) * SB * 2304]);
          a3 = fmaxf(a3, pp[(size_t)(cc + 3) * SB * 2304]);
        }
        for (; cc < nv; ++cc) a0 = fmaxf(a0, pp[(size_t)cc * SB * 2304]);
        ptrad[b * 2304 + jj] = fmaxf(fmaxf(a0, a1), fmaxf(a2, a3));
      } else {
        float a0 = -NEG_INF, a1 = -NEG_INF, a2 = -NEG_INF, a3 = -NEG_INF;
        int cc = 0;
        for (; cc + 4 <= nv; cc += 4) {
          a0 = fminf(a0, pp[(size_t)(cc    ) * SB * 2304]);
          a1 = fminf(a1, pp[(size_t)(cc + 1) * SB * 2304]);
          a2 = fminf(a2, pp[(size_t)(cc + 2) * SB * 2304]);
          a3 = fminf(a3, pp[(size_t)(cc + 3) * SB * 2304]);
        }
        for (; cc < nv; ++cc) a0 = fminf(a0, pp[(size_t)cc * SB * 2304]);
        ptrad[b * 2304 + jj] = fminf(fminf(a0, a1), fminf(a2, a3));
      }
    } else if (jj < 8448) {
      int t = jj - 2304;
      int m = t / SD;
      const float* po = pO + t + (size_t)b * 6144;
      float a0 = 0.f, a1 = 0.f, a2 = 0.f, a3 = 0.f;
      float a4 = 0.f, a5 = 0.f, a6 = 0.f, a7 = 0.f;
      int cc = 0;
      for (; cc + 8 <= nv; cc += 8) {
        a0 += po[(size_t)(cc    ) * SB * 6144] * e_lds[cc    ][m];
        a1 += po[(size_t)(cc + 1) * SB * 6144] * e_lds[cc + 1][m];
        a2 += po[(size_t)(cc + 2) * SB * 6144] * e_lds[cc + 2][m];
        a3 += po[(size_t)(cc + 3) * SB * 6144] * e_lds[cc + 3][m];
        a4 += po[(size_t)(cc + 4) * SB * 6144] * e_lds[cc + 4][m];
        a5 += po[(size_t)(cc + 5) * SB * 6144] * e_lds[cc + 5][m];
        a6 += po[(size_t)(cc + 6) * SB * 6144] * e_lds[cc + 6][m];
        a7 += po[(size_t)(cc + 7) * SB * 6144] * e_lds[cc + 7][m];
      }
      for (; cc < nv; ++cc) a0 += po[(size_t)cc * SB * 6144] * e_lds[cc][m];
      plearn[b * 6912 + t] = (((a0 + a1) + (a2 + a3)) + ((a4 + a5) + (a6 + a7))) * Linv_lds[m];
    } else {
      int dd = jj - 8448;
      plearn[b * 6912 + 6144 + dd] = tokens[(size_t)b * TOK_ROW * SD + dd];
    }
  }
}

// ============ split-K GEMM partial: (16 x K) @ (K x 768), k-tile = 128 ========
__global__ __launch_bounds__(256) void gemm_partial(
    const float* __restrict__ XA, const float* __restrict__ WA, int ktA, float* __restrict__ PA,
    const float* __restrict__ XB, const float* __restrict__ WB, float* __restrict__ PB) {
  int nt = blockIdx.x, ky = blockIdx.y;
  const float *X, *W; float* P; int kt, ktN;
  if (ky < ktA) { X = XA; W = WA; P = PA; kt = ky; ktN = ktA; }
  else { X = XB; W = WB; P = PB; kt = ky - ktA; ktN = gridDim.y - ktA; }
  int K = ktN * 128;
  int k0 = kt * 128;
  __shared__ __align__(16) float xt[128 * 20];
  __shared__ float red[4][64][17];
  int tid = threadIdx.x;
  int kk = tid & 127, half = tid >> 7;
  #pragma unroll
  for (int u = 0; u < 8; ++u) {
    int b2 = half * 8 + u;
    xt[kk * 20 + b2] = X[b2 * K + k0 + kk];
  }
  __syncthreads();
  int w = tid >> 6, lane = tid & 63;
  int n = nt * 64 + lane;
  float acc[16];
  #pragma unroll
  for (int b2 = 0; b2 < 16; ++b2) acc[b2] = 0.f;
  const float* Wp = W + (size_t)k0 * SD + n;
  #pragma unroll 8
  for (int kj = 0; kj < 32; ++kj) {
    int k = w + kj * 4;
    float wv = Wp[(size_t)k * SD];
    const float4* xr = reinterpret_cast<const float4*>(xt + k * 20);
    float4 a0 = xr[0], a1 = xr[1], a2 = xr[2], a3 = xr[3];
    acc[0] += wv * a0.x; acc[1] += wv * a0.y; acc[2] += wv * a0.z; acc[3] += wv * a0.w;
    acc[4] += wv * a1.x; acc[5] += wv * a1.y; acc[6] += wv * a1.z; acc[7] += wv * a1.w;
    acc[8] += wv * a2.x; acc[9] += wv * a2.y; acc[10] += wv * a2.z; acc[11] += wv * a2.w;
    acc[12] += wv * a3.x; acc[13] += wv * a3.y; acc[14] += wv * a3.z; acc[15] += wv * a3.w;
  }
  #pragma unroll
  for (int b2 = 0; b2 < 16; ++b2) red[w][lane][b2] = acc[b2];
  __syncthreads();
  for (int i = tid; i < 1024; i += 256) {
    int nn = i & 63, b2 = i >> 6;
    float r = red[0][nn][b2] + red[1][nn][b2] + red[2][nn][b2] + red[3][nn][b2];
    P[(size_t)(kt * 16 + b2) * SD + nt * 64 + nn] = r;
  }
}

// ============ reduce + bias + exact GELU (compile-time trip counts) ===========
__global__ void gelu_reduce(const float* __restrict__ PA, const float* __restrict__ b1a,
                            float* __restrict__ HA, const float* __restrict__ PB,
                            const float* __restrict__ b1b, float* __restrict__ HB) {
  int y = blockIdx.y;
  int j = blockIdx.x * 256 + threadIdx.x;  // < 12288
  float r;
  if (y == 0) {
    r = b1a[j % SD];
    #pragma unroll
    for (int kt = 0; kt < 18; ++kt) r += PA[kt * 12288 + j];
    HA[j] = r * 0.5f * (1.f + erff(r * 0.70710678118654752f));
  } else {
    r = b1b[j % SD];
    #pragma unroll
    for (int kt = 0; kt < 54; ++kt) r += PB[kt * 12288 + j];
    HB[j] = r * 0.5f * (1.f + erff(r * 0.70710678118654752f));
  }
}

// ============ final: reduce 6 partials + bias -> d_out ========================
__global__ void final_reduce(const float* __restrict__ P2A, const float* __restrict__ b2a,
                             const float* __restrict__ P2B, const float* __restrict__ b2b,
                             float* __restrict__ out) {
  int y = blockIdx.y;
  const float* P = y ? P2B : P2A;
  const float* bias = y ? b2b : b2a;
  int j = blockIdx.x * 256 + threadIdx.x;  // < 12288
  float r = bias[j % SD];
  #pragma unroll
  for (int kt = 0; kt < 6; ++kt) r += P[kt * 12288 + j];
  int b = j / SD, nn = j - b * SD;
  out[b * 1536 + y * SD + nn] = r;
}

extern "C" void kernel_launch(void* const* d_in, const int* in_sizes, int n_in,
                              void* d_out, int out_size, void* d_ws, size_t ws_size,
                              hipStream_t stream) {
  const float* tokens = (const float*)d_in[0];
  const int* lengths  = (const int*)d_in[1];
  const float* q      = (const float*)d_in[2];
  const float* lns    = (const float*)d_in[3];
  const float* lnb    = (const float*)d_in[4];
  const float* w1a    = (const float*)d_in[5];
  const float* b1a    = (const float*)d_in[6];
  const float* w2a    = (const float*)d_in[7];
  const float* b2a    = (const float*)d_in[8];
  const float* w1b    = (const float*)d_in[9];
  const float* b1b    = (const float*)d_in[10];
  const float* w2b    = (const float*)d_in[11];
  const float* b2b    = (const float*)d_in[12];
  float* ws  = (float*)d_ws;
  float* out = (float*)d_out;

  float* ppool  = ws + OFF_PPOOL;
  float* pO     = ws + OFF_PO;
  float* pml    = ws + OFF_PML;
  float* ptrad  = ws + OFF_PTRAD;
  float* plearn = ws + OFF_PLEARN;
  float* p1a    = ws + OFF_P1A;
  float* p1b    = ws + OFF_P1B;
  float* ha     = ws + OFF_HA;
  float* hb     = ws + OFF_HB;
  float* p2a    = ws + OFF_P2A;
  float* p2b    = ws + OFF_P2B;

  k1_flash<<<dim3(32, 16), 256, 0, stream>>>(tokens, lengths, q, lns, lnb, ppool, pO, pml);
  k_combine<<<dim3(9, 16), 256, 0, stream>>>(ppool, pO, pml, tokens, lengths, ptrad, plearn);
  gemm_partial<<<dim3(12, 72), 256, 0, stream>>>(ptrad, w1a, 18, p1a, plearn, w1b, p1b);
  gelu_reduce<<<dim3(48, 2), 256, 0, stream>>>(p1a, b1a, ha, p1b, b1b, hb);
  gemm_partial<<<dim3(12, 12), 256, 0, stream>>>(ha, w2a, 6, p2a, hb, w2b, p2b);
  final_reduce<<<dim3(48, 2), 256, 0, stream>>>(p2a, b2a, p2b, b2b, out);
}